// Round 4
// baseline (143.271 us; speedup 1.0000x reference)
//
#include <hip/hip_runtime.h>
#include <cmath>

#define BLOCK 256
#define CH 8    // k-chunk per staging group

// acc layout: per batch b, 4 floats [pos_count, stc_sum, str_sum, pad].
// Zeroed by memsetAsync. Finalization is a separate kernel (stream-ordered).
__global__ void __launch_bounds__(BLOCK) ainno_main(
    const float* __restrict__ ss,       // (B, A, 6)
    const float* __restrict__ anchors,  // (A, 4) xywh
    const float* __restrict__ gt,       // (B, K, 4) xywh
    float* __restrict__ acc,
    int A, int K, int B)
{
    // K <= 64. Derived GT boxes staged once per block.
    __shared__ float4 gxy_s[64];
    __shared__ float  gar_s[64];
    __shared__ float  red[(BLOCK / 64) * 3];

    const int b    = blockIdx.y;
    const int tid  = threadIdx.x;
    const int lane = tid & 63;

    if (tid < K) {
        // Same arithmetic as reference: x2 = x + w, area = (x2-x)*(y2-y).
        float4 g = ((const float4*)(gt + (size_t)b * K * 4))[tid];
        float x2 = g.x + g.z, y2 = g.y + g.w;
        gxy_s[tid] = make_float4(g.x, g.y, x2, y2);
        gar_s[tid] = (x2 - g.x) * (y2 - g.y);
    }

    // APT=1: one anchor per thread -> 1876 blocks = 7504 waves = 7.3/SIMD
    // (92% of HW wave capacity). Round-1's APT=1 regression was confounded
    // by (a) readlane de-amortization (now: LDS broadcast, off-VALU) and
    // (b) the per-block threadfence+contended-counter protocol (now: split
    // finalize kernel). Per-anchor VALU work is unchanged vs APT=2; the
    // extra waves cover the dependence/LDS stalls that held VALUBusy at 34%.
    const int a  = blockIdx.x * BLOCK + tid;
    const int ac = a < A ? a : A - 1;      // clamp; contribution guarded later
    float4 an = ((const float4*)anchors)[ac];
    const float ax  = an.x,        ay  = an.y;
    const float axx = an.x + an.z, ayy = an.y + an.w;
    const float aar = (axx - ax) * (ayy - ay);

    // Prefetch the logit: issued here, first consumed after the K-loop, so
    // its ~900cy HBM latency hides under the hot loop instead of being
    // exposed in the epilogue. (Nearly every anchor is pos or neg, so this
    // load is ~never wasted.)
    const float* sp = ss + ((size_t)b * A + ac) * 6;
    float x_logit = sp[4];

    float bi = -1.f, bd = 1.f;
    int   bk = 0;

    __syncthreads();

    // Hot loop. Argmax over iou = inter/(S - inter), S = aar + sar:
    // x/(S-x) monotone in x/S => candidate beats best <=> inter*bd > bi*S
    // (cross-multiplied, exact operands, no divide). Strict > keeps the
    // first max, matching the reference argmax.
    const int kfull = K & ~(CH - 1);
    for (int k0 = 0; k0 < kfull; k0 += CH) {
        float4 gg[CH];
        float  sar[CH];
        #pragma unroll
        for (int j = 0; j < CH; ++j) {
            gg[j]  = gxy_s[k0 + j];   // ds_read_b128, uniform addr -> broadcast
            sar[j] = gar_s[k0 + j];   // ds_read_b32
        }
        #pragma unroll
        for (int j = 0; j < CH; ++j) {
            float w = fminf(axx, gg[j].z) - fmaxf(ax, gg[j].x);
            float h = fminf(ayy, gg[j].w) - fmaxf(ay, gg[j].y);
            w = fmaxf(w, 0.f); h = fmaxf(h, 0.f);
            float inter = w * h;
            float S = aar + sar[j];
            bool better = inter * bd > bi * S;
            bi = better ? inter : bi;
            bd = better ? S     : bd;
            bk = better ? (k0 + j) : bk;
        }
    }
    for (int k = kfull; k < K; ++k) {    // tail (not taken for K=64)
        float4 gg  = gxy_s[k];
        float  sar = gar_s[k];
        float w = fminf(axx, gg.z) - fmaxf(ax, gg.x);
        float h = fminf(ayy, gg.w) - fmaxf(ay, gg.y);
        w = fmaxf(w, 0.f); h = fmaxf(h, 0.f);
        float inter = w * h;
        float S = aar + sar;
        bool better = inter * bd > bi * S;
        bi = better ? inter : bi;
        bd = better ? S     : bd;
        bk = better ? k     : bk;
    }

    float posf = 0.f, stcs = 0.f, strs = 0.f;
    {
        // Winner box straight from LDS (divergent one-time gather).
        float4 wb  = gxy_s[bk];
        float  war = gar_s[bk];

        // score == ref max IoU bit-identically: bd - bi = (aar+sar) - inter,
        // same operand order as reference's (area_a + area_g) - inter.
        float score = bi / (bd - bi);
        bool inb = a < A;
        bool pos = inb && (score >= 0.5f);
        bool neg = inb && (score < 0.4f);
        if (pos | neg) {
            float x = x_logit;
            float e = expf(-x);
            float p = 1.f / (1.f + e);
            if (pos) {
                posf += 1.f;
                float ce  = log1pf(e);           // softplus(-x) = -log_sigmoid(x)
                float omp = 1.f - p;
                stcs += 0.25f * ce * omp * omp;

                float px  = sp[0], py = sp[1];
                float pxx = px + sp[2], pyy = py + sp[3];
                float ew = fminf(pxx, wb.z) - fmaxf(px, wb.x);
                float eh = fminf(pyy, wb.w) - fmaxf(py, wb.y);
                ew = fmaxf(ew, 0.f); eh = fmaxf(eh, 0.f);
                float einter = ew * eh;
                float pa = (pxx - px) * (pyy - py);
                float eiou = einter / (pa + war - einter);
                strs += -logf(eiou + 0.01f);
            } else {
                float ce = log1pf(expf(x));      // softplus(x) = -log_sigmoid(-x)
                stcs += 0.75f * ce * p * p;
            }
        }
    }

    // wave64 shuffle reduction -> LDS across waves -> 3 atomics per block
    float v0 = posf, v1 = stcs, v2 = strs;
    for (int off = 32; off > 0; off >>= 1) {
        v0 += __shfl_down(v0, off, 64);
        v1 += __shfl_down(v1, off, 64);
        v2 += __shfl_down(v2, off, 64);
    }
    const int wave = tid >> 6;
    if (lane == 0) {
        red[wave * 3 + 0] = v0;
        red[wave * 3 + 1] = v1;
        red[wave * 3 + 2] = v2;
    }
    __syncthreads();
    if (tid == 0) {
        float s0 = 0.f, s1 = 0.f, s2 = 0.f;
        for (int w = 0; w < BLOCK / 64; ++w) {
            s0 += red[w * 3 + 0];
            s1 += red[w * 3 + 1];
            s2 += red[w * 3 + 2];
        }
        atomicAdd(&acc[b * 4 + 0], s0);
        atomicAdd(&acc[b * 4 + 1], s1);
        atomicAdd(&acc[b * 4 + 2], s2);
    }
}

// Separate finalize kernel: stream ordering guarantees visibility of the
// main kernel's device-scope atomics -> plain loads are safe here.
__global__ void ainno_final(const float* __restrict__ acc,
                            float* __restrict__ out, int B)
{
    if (threadIdx.x == 0 && blockIdx.x == 0) {
        float tot = 0.f;
        for (int bb = 0; bb < B; ++bb) {
            float pc = acc[bb * 4 + 0];
            float st = acc[bb * 4 + 1];
            float sr = acc[bb * 4 + 2];
            float safe = pc > 0.f ? pc : 1.f;
            tot += st / safe;
            if (pc > 0.f) tot += sr / safe;
        }
        out[0] = tot / (float)B;
    }
}

extern "C" void kernel_launch(void* const* d_in, const int* in_sizes, int n_in,
                              void* d_out, int out_size, void* d_ws, size_t ws_size,
                              hipStream_t stream) {
    const float* ss      = (const float*)d_in[0];
    const float* anchors = (const float*)d_in[1];
    const float* gt      = (const float*)d_in[2];
    float* out = (float*)d_out;
    float* acc = (float*)d_ws;

    const int A = in_sizes[1] / 4;
    const int B = in_sizes[0] / (A * 6);
    const int K = in_sizes[2] / (B * 4);

    // zero accumulators (d_ws is poisoned each call)
    hipMemsetAsync(acc, 0, (size_t)B * 4 * sizeof(float), stream);

    dim3 grid((A + BLOCK - 1) / BLOCK, B);
    ainno_main<<<grid, BLOCK, 0, stream>>>(ss, anchors, gt, acc, A, K, B);
    ainno_final<<<dim3(1), 64, 0, stream>>>(acc, out, B);
}

// Round 5
// 143.185 us; speedup vs baseline: 1.0006x; 1.0006x over previous
//
#include <hip/hip_runtime.h>
#include <cmath>

#define BLOCK 512   // 8 waves/block
#define GXMAX 64    // grid.x cap: 64 * B(=4) = 256 blocks = 1 block/CU.
                    // Empirical scaling law (r0-r4): wall ~ 35-50 ns per
                    // workgroup at fixed total work -> minimize WG count.

// acc layout: per batch b, 4 floats [pos_count, stc_sum, str_sum, pad].
// Zeroed by memsetAsync. Finalization is a separate kernel (stream-ordered).
__global__ void __launch_bounds__(BLOCK) ainno_main(
    const float* __restrict__ ss,       // (B, A, 6)
    const float* __restrict__ anchors,  // (A, 4) xywh
    const float* __restrict__ gt,       // (B, K, 4) xywh
    float* __restrict__ acc,
    int A, int K, int B)
{
    // K <= 64. GT boxes as xyxy staged once per block. Area is NOT staged:
    // sar = (x2-x1)*(y2-y1) recomputed in VALU (bit-identical expression,
    // 3 ops) -- halves LDS-pipe issue pressure in the hot loop.
    __shared__ float4 gxy_s[64];
    __shared__ float  red[(BLOCK / 64) * 3];

    const int b    = blockIdx.y;
    const int tid  = threadIdx.x;
    const int lane = tid & 63;

    if (tid < K) {
        // Same arithmetic as reference: x2 = x + w.
        float4 g = ((const float4*)(gt + (size_t)b * K * 4))[tid];
        gxy_s[tid] = make_float4(g.x, g.y, g.x + g.z, g.y + g.w);
    }
    __syncthreads();

    const int ntiles = (A + BLOCK - 1) / BLOCK;
    float posf = 0.f, stcs = 0.f, strs = 0.f;

    // Grid-stride over anchor tiles: ~3-4 tiles/block at A=120000.
    for (int tt = blockIdx.x; tt < ntiles; tt += gridDim.x) {
        const int a  = tt * BLOCK + tid;
        const int ac = a < A ? a : A - 1;   // clamp; contribution guarded later
        float4 an = ((const float4*)anchors)[ac];
        const float ax  = an.x,        ay  = an.y;
        const float axx = an.x + an.z, ayy = an.y + an.w;
        const float aar = (axx - ax) * (ayy - ay);

        // Prefetch logit: issued before the K-loop, consumed after -> HBM
        // latency hides under ~2k cycles of IoU math.
        const float* sp = ss + ((size_t)b * A + ac) * 6;
        float x_logit = sp[4];

        // Argmax over iou = inter/(S - inter), S = aar + sar: x/(S-x) is
        // monotone in x/S => candidate beats best <=> inter*bd > bi*S
        // (cross-multiplied, exact operands, no divide).
        // 4 INDEPENDENT chains over k-quarters (dep-chain 16 not 64; with
        // 1 block/CU = 2 waves/SIMD, latency hiding must come from ILP).
        // Merging in index order with strict > keeps the lowest-k winner on
        // exact ties, preserving reference first-max semantics.
        float bi[4] = {-1.f, -1.f, -1.f, -1.f};
        float bd[4] = { 1.f,  1.f,  1.f,  1.f};
        int   bk[4] = { 0, 0, 0, 0 };

        if (K == 64) {
            #pragma unroll
            for (int kk = 0; kk < 16; ++kk) {
                #pragma unroll
                for (int c = 0; c < 4; ++c) {
                    // compile-time LDS offset: ds_read_b128 offset:N, no
                    // address VALU; uniform addr -> broadcast, conflict-free
                    float4 gg = gxy_s[c * 16 + kk];
                    float w = fminf(axx, gg.z) - fmaxf(ax, gg.x);
                    float h = fminf(ayy, gg.w) - fmaxf(ay, gg.y);
                    w = fmaxf(w, 0.f); h = fmaxf(h, 0.f);
                    float inter = w * h;
                    float sar = (gg.z - gg.x) * (gg.w - gg.y);
                    float S = aar + sar;
                    bool better = inter * bd[c] > bi[c] * S;
                    bi[c] = better ? inter       : bi[c];
                    bd[c] = better ? S           : bd[c];
                    bk[c] = better ? c * 16 + kk : bk[c];
                }
            }
        } else {
            // generic fallback: single sequential chain (chain 0)
            for (int k = 0; k < K; ++k) {
                float4 gg = gxy_s[k];
                float w = fminf(axx, gg.z) - fmaxf(ax, gg.x);
                float h = fminf(ayy, gg.w) - fmaxf(ay, gg.y);
                w = fmaxf(w, 0.f); h = fmaxf(h, 0.f);
                float inter = w * h;
                float sar = (gg.z - gg.x) * (gg.w - gg.y);
                float S = aar + sar;
                bool better = inter * bd[0] > bi[0] * S;
                bi[0] = better ? inter : bi[0];
                bd[0] = better ? S     : bd[0];
                bk[0] = better ? k     : bk[0];
            }
        }

        // Ordered merge: strict > so exact ties keep the lower-k incumbent.
        float Bi = bi[0], Bd = bd[0];
        int   Bk = bk[0];
        #pragma unroll
        for (int c = 1; c < 4; ++c) {
            bool better = bi[c] * Bd > Bi * bd[c];
            Bi = better ? bi[c] : Bi;
            Bd = better ? bd[c] : Bd;
            Bk = better ? bk[c] : Bk;
        }

        {
            // Winner box from LDS (divergent one-time gather); its area
            // recomputed with the identical expression.
            float4 wb  = gxy_s[Bk];
            float  war = (wb.z - wb.x) * (wb.w - wb.y);

            // score == ref max IoU bit-identically: Bd - Bi = (aar+sar) -
            // inter, same operand order as ref (area_a + area_g) - inter.
            float score = Bi / (Bd - Bi);
            bool inb = a < A;
            bool pos = inb && (score >= 0.5f);
            bool neg = inb && (score < 0.4f);
            if (pos | neg) {
                float x = x_logit;
                float e = expf(-x);
                float p = 1.f / (1.f + e);
                if (pos) {
                    posf += 1.f;
                    float ce  = log1pf(e);        // softplus(-x) = -log_sigmoid(x)
                    float omp = 1.f - p;
                    stcs += 0.25f * ce * omp * omp;

                    float px  = sp[0], py = sp[1];
                    float pxx = px + sp[2], pyy = py + sp[3];
                    float ew = fminf(pxx, wb.z) - fmaxf(px, wb.x);
                    float eh = fminf(pyy, wb.w) - fmaxf(py, wb.y);
                    ew = fmaxf(ew, 0.f); eh = fmaxf(eh, 0.f);
                    float einter = ew * eh;
                    float pa = (pxx - px) * (pyy - py);
                    float eiou = einter / (pa + war - einter);
                    strs += -logf(eiou + 0.01f);
                } else {
                    float ce = log1pf(expf(x));   // softplus(x) = -log_sigmoid(-x)
                    stcs += 0.75f * ce * p * p;
                }
            }
        }
    }

    // wave64 shuffle reduction -> LDS across waves -> 3 atomics per block
    float v0 = posf, v1 = stcs, v2 = strs;
    for (int off = 32; off > 0; off >>= 1) {
        v0 += __shfl_down(v0, off, 64);
        v1 += __shfl_down(v1, off, 64);
        v2 += __shfl_down(v2, off, 64);
    }
    const int wave = tid >> 6;
    if (lane == 0) {
        red[wave * 3 + 0] = v0;
        red[wave * 3 + 1] = v1;
        red[wave * 3 + 2] = v2;
    }
    __syncthreads();
    if (tid == 0) {
        float s0 = 0.f, s1 = 0.f, s2 = 0.f;
        for (int w = 0; w < BLOCK / 64; ++w) {
            s0 += red[w * 3 + 0];
            s1 += red[w * 3 + 1];
            s2 += red[w * 3 + 2];
        }
        atomicAdd(&acc[b * 4 + 0], s0);
        atomicAdd(&acc[b * 4 + 1], s1);
        atomicAdd(&acc[b * 4 + 2], s2);
    }
}

// Separate finalize kernel: stream ordering guarantees visibility of the
// main kernel's device-scope atomics -> plain loads are safe here.
__global__ void ainno_final(const float* __restrict__ acc,
                            float* __restrict__ out, int B)
{
    if (threadIdx.x == 0 && blockIdx.x == 0) {
        float tot = 0.f;
        for (int bb = 0; bb < B; ++bb) {
            float pc = acc[bb * 4 + 0];
            float st = acc[bb * 4 + 1];
            float sr = acc[bb * 4 + 2];
            float safe = pc > 0.f ? pc : 1.f;
            tot += st / safe;
            if (pc > 0.f) tot += sr / safe;
        }
        out[0] = tot / (float)B;
    }
}

extern "C" void kernel_launch(void* const* d_in, const int* in_sizes, int n_in,
                              void* d_out, int out_size, void* d_ws, size_t ws_size,
                              hipStream_t stream) {
    const float* ss      = (const float*)d_in[0];
    const float* anchors = (const float*)d_in[1];
    const float* gt      = (const float*)d_in[2];
    float* out = (float*)d_out;
    float* acc = (float*)d_ws;

    const int A = in_sizes[1] / 4;
    const int B = in_sizes[0] / (A * 6);
    const int K = in_sizes[2] / (B * 4);

    // zero accumulators (d_ws is poisoned each call)
    hipMemsetAsync(acc, 0, (size_t)B * 4 * sizeof(float), stream);

    const int ntiles = (A + BLOCK - 1) / BLOCK;
    const int gx = ntiles < GXMAX ? ntiles : GXMAX;
    dim3 grid(gx, B);
    ainno_main<<<grid, BLOCK, 0, stream>>>(ss, anchors, gt, acc, A, K, B);
    ainno_final<<<dim3(1), 64, 0, stream>>>(acc, out, B);
}

// Round 6
// 94.272 us; speedup vs baseline: 1.5198x; 1.5189x over previous
//
#include <hip/hip_runtime.h>
#include <cmath>

#define BLOCK 256
#define APT 2    // anchors per thread per tile (proven r2/r3 inner loop)
#define CH 8     // k-chunk staged per group (runtime chunk idx: blocks r5-style
                 // whole-loop hoist -> no spill; VGPR stayed 32 in r3)
#define TILES 4  // target tiles per block -> grid.x 235 -> 59, WGs 940 -> 236

// part layout: per (b, gx) one float4 [pos_count, stc_sum, str_sum, pad],
// plain-stored by the owning block (no atomics, no zero-init -> no memset
// node). Finalize kernel (stream-ordered) sums the slots.
__global__ void __launch_bounds__(BLOCK) ainno_main(
    const float* __restrict__ ss,       // (B, A, 6)
    const float* __restrict__ anchors,  // (A, 4) xywh
    const float* __restrict__ gt,       // (B, K, 4) xywh
    float* __restrict__ part,           // (B, gridDim.x, 4)
    int A, int K, int B)
{
    // K <= 64. Derived GT boxes staged once per block (shared by all tiles).
    __shared__ float4 gxy_s[64];
    __shared__ float  gar_s[64];
    __shared__ float  red[(BLOCK / 64) * 3];

    const int b    = blockIdx.y;
    const int tid  = threadIdx.x;
    const int lane = tid & 63;

    if (tid < K) {
        // Same arithmetic as reference: x2 = x + w, area = (x2-x)*(y2-y).
        float4 g = ((const float4*)(gt + (size_t)b * K * 4))[tid];
        float x2 = g.x + g.z, y2 = g.y + g.w;
        gxy_s[tid] = make_float4(g.x, g.y, x2, y2);
        gar_s[tid] = (x2 - g.x) * (y2 - g.y);
    }
    __syncthreads();

    const int tileSz = BLOCK * APT;
    const int ntiles = (A + tileSz - 1) / tileSz;

    float posf = 0.f, stcs = 0.f, strs = 0.f;

    // Grid-stride over anchor tiles (~4 tiles/block at A=120000, gx=59).
    for (int tt = blockIdx.x; tt < ntiles; tt += gridDim.x) {
        const int base = tt * tileSz + tid;

        float ax[APT], ay[APT], axx[APT], ayy[APT], aar[APT];
        float bi[APT], bd[APT];
        int   bk[APT];
        #pragma unroll
        for (int i = 0; i < APT; ++i) {
            int a  = base + i * BLOCK;
            int ac = a < A ? a : A - 1;  // clamp; contribution guarded later
            float4 an = ((const float4*)anchors)[ac];
            ax[i]  = an.x;         ay[i]  = an.y;
            axx[i] = an.x + an.z;  ayy[i] = an.y + an.w;
            aar[i] = (axx[i] - ax[i]) * (ayy[i] - ay[i]);
            bi[i] = -1.f; bd[i] = 1.f; bk[i] = 0;
        }

        // Hot loop: EXACT r2/r3 structure (proven codegen, VGPR 32).
        // Argmax over iou = inter/(S - inter), S = aar + sar: x/(S-x) is
        // monotone in x/S => candidate beats best <=> inter*bd > bi*S
        // (cross-multiplied, exact operands, no divide). Strict > keeps
        // the first max, matching the reference argmax.
        const int kfull = K & ~(CH - 1);
        for (int k0 = 0; k0 < kfull; k0 += CH) {
            float4 gg[CH];
            float  sar[CH];
            #pragma unroll
            for (int j = 0; j < CH; ++j) {
                gg[j]  = gxy_s[k0 + j];  // ds_read_b128, uniform -> broadcast
                sar[j] = gar_s[k0 + j];  // ds_read_b32
            }
            #pragma unroll
            for (int j = 0; j < CH; ++j) {
                #pragma unroll
                for (int i = 0; i < APT; ++i) {
                    float w = fminf(axx[i], gg[j].z) - fmaxf(ax[i], gg[j].x);
                    float h = fminf(ayy[i], gg[j].w) - fmaxf(ay[i], gg[j].y);
                    w = fmaxf(w, 0.f); h = fmaxf(h, 0.f);
                    float inter = w * h;
                    float S = aar[i] + sar[j];
                    bool better = inter * bd[i] > bi[i] * S;
                    bi[i] = better ? inter : bi[i];
                    bd[i] = better ? S     : bd[i];
                    bk[i] = better ? (k0 + j) : bk[i];
                }
            }
        }
        for (int k = kfull; k < K; ++k) {   // tail (not taken for K=64)
            float4 gg  = gxy_s[k];
            float  sar = gar_s[k];
            #pragma unroll
            for (int i = 0; i < APT; ++i) {
                float w = fminf(axx[i], gg.z) - fmaxf(ax[i], gg.x);
                float h = fminf(ayy[i], gg.w) - fmaxf(ay[i], gg.y);
                w = fmaxf(w, 0.f); h = fmaxf(h, 0.f);
                float inter = w * h;
                float S = aar[i] + sar;
                bool better = inter * bd[i] > bi[i] * S;
                bi[i] = better ? inter : bi[i];
                bd[i] = better ? S     : bd[i];
                bk[i] = better ? k     : bk[i];
            }
        }

        #pragma unroll
        for (int i = 0; i < APT; ++i) {
            int a = base + i * BLOCK;
            // Winner box straight from LDS (divergent one-time gather).
            float4 wb  = gxy_s[bk[i]];
            float  war = gar_s[bk[i]];

            // score == ref max IoU bit-identically: bd-bi = (aar+sar)-inter,
            // same operand order as reference's (area_a + area_g) - inter.
            float score = bi[i] / (bd[i] - bi[i]);
            bool inb = a < A;
            bool pos = inb && (score >= 0.5f);
            bool neg = inb && (score < 0.4f);
            if (pos | neg) {
                const float* sp = ss + ((size_t)b * A + a) * 6;
                float x = sp[4];
                float e = expf(-x);
                float p = 1.f / (1.f + e);
                if (pos) {
                    posf += 1.f;
                    float ce  = log1pf(e);        // softplus(-x) = -log_sigmoid(x)
                    float omp = 1.f - p;
                    stcs += 0.25f * ce * omp * omp;

                    float px  = sp[0], py = sp[1];
                    float pxx = px + sp[2], pyy = py + sp[3];
                    float ew = fminf(pxx, wb.z) - fmaxf(px, wb.x);
                    float eh = fminf(pyy, wb.w) - fmaxf(py, wb.y);
                    ew = fmaxf(ew, 0.f); eh = fmaxf(eh, 0.f);
                    float einter = ew * eh;
                    float pa = (pxx - px) * (pyy - py);
                    float eiou = einter / (pa + war - einter);
                    strs += -logf(eiou + 0.01f);
                } else {
                    float ce = log1pf(expf(x));   // softplus(x) = -log_sigmoid(-x)
                    stcs += 0.75f * ce * p * p;
                }
            }
        }
    }

    // wave64 shuffle reduction -> LDS across waves -> one plain float4 store
    float v0 = posf, v1 = stcs, v2 = strs;
    for (int off = 32; off > 0; off >>= 1) {
        v0 += __shfl_down(v0, off, 64);
        v1 += __shfl_down(v1, off, 64);
        v2 += __shfl_down(v2, off, 64);
    }
    const int wave = tid >> 6;
    if (lane == 0) {
        red[wave * 3 + 0] = v0;
        red[wave * 3 + 1] = v1;
        red[wave * 3 + 2] = v2;
    }
    __syncthreads();
    if (tid == 0) {
        float s0 = 0.f, s1 = 0.f, s2 = 0.f;
        for (int w = 0; w < BLOCK / 64; ++w) {
            s0 += red[w * 3 + 0];
            s1 += red[w * 3 + 1];
            s2 += red[w * 3 + 2];
        }
        // Own slot, plain store: no atomics, no pre-zeroed memory needed.
        ((float4*)part)[(size_t)b * gridDim.x + blockIdx.x] =
            make_float4(s0, s1, s2, 0.f);
    }
}

// Finalize: stream ordering guarantees visibility of main's stores.
// Sums the (B x GX) partial slots and applies the per-batch normalization.
__global__ void ainno_final(const float* __restrict__ part,
                            float* __restrict__ out, int GX, int B)
{
    __shared__ float tot_s[4];
    const int tid = threadIdx.x, lane = tid & 63, wave = tid >> 6; // 4 waves
    float t = 0.f;
    for (int bb = wave; bb < B; bb += 4) {
        float pc = 0.f, st = 0.f, sr = 0.f;
        for (int i = lane; i < GX; i += 64) {
            const float* p = part + ((size_t)bb * GX + i) * 4;
            pc += p[0]; st += p[1]; sr += p[2];
        }
        for (int off = 32; off > 0; off >>= 1) {
            pc += __shfl_down(pc, off, 64);
            st += __shfl_down(st, off, 64);
            sr += __shfl_down(sr, off, 64);
        }
        if (lane == 0) {
            float safe = pc > 0.f ? pc : 1.f;
            float v = st / safe;
            if (pc > 0.f) v += sr / safe;
            t += v;
        }
    }
    if (lane == 0) tot_s[wave] = t;
    __syncthreads();
    if (tid == 0) {
        float s = 0.f;
        for (int w = 0; w < 4; ++w) s += tot_s[w];
        out[0] = s / (float)B;
    }
}

extern "C" void kernel_launch(void* const* d_in, const int* in_sizes, int n_in,
                              void* d_out, int out_size, void* d_ws, size_t ws_size,
                              hipStream_t stream) {
    const float* ss      = (const float*)d_in[0];
    const float* anchors = (const float*)d_in[1];
    const float* gt      = (const float*)d_in[2];
    float* out  = (float*)d_out;
    float* part = (float*)d_ws;

    const int A = in_sizes[1] / 4;
    const int B = in_sizes[0] / (A * 6);
    const int K = in_sizes[2] / (B * 4);

    const int tileSz = BLOCK * APT;
    const int ntiles = (A + tileSz - 1) / tileSz;        // 235 at A=120000
    const int gx     = (ntiles + TILES - 1) / TILES;     // 59 -> 236 WGs

    dim3 grid(gx, B);
    ainno_main<<<grid, BLOCK, 0, stream>>>(ss, anchors, gt, part, A, K, B);
    ainno_final<<<dim3(1), 256, 0, stream>>>(part, out, gx, B);
}

// Round 7
// 83.732 us; speedup vs baseline: 1.7111x; 1.1259x over previous
//
#include <hip/hip_runtime.h>
#include <cmath>

#define BLOCK 1024  // 16 waves/block: same 236-WG geometry as round 6 but
                    // 4 waves/SIMD instead of 1 (round 6 had zero TLP; the
                    // WG-cost law (r0-r6) punishes workgroups, not waves).
#define APT 2       // anchors per thread (proven r2/r3/r6 inner loop)
#define CH 8        // k-chunk staged per group (runtime chunk idx prevents
                    // r5-style whole-loop hoist/spill; VGPR stayed ~32)

// part layout: per (b, gx) one float4 [pos_count, stc_sum, str_sum, pad],
// plain-stored by the owning block (no atomics, no zero-init, no memset
// node). Finalize kernel (stream-ordered) sums the slots.
__global__ void __launch_bounds__(BLOCK) ainno_main(
    const float* __restrict__ ss,       // (B, A, 6)
    const float* __restrict__ anchors,  // (A, 4) xywh
    const float* __restrict__ gt,       // (B, K, 4) xywh
    float* __restrict__ part,           // (B, gridDim.x, 4)
    int A, int K, int B)
{
    // K <= 64. Derived GT boxes staged once per block.
    __shared__ float4 gxy_s[64];
    __shared__ float  gar_s[64];
    __shared__ float  red[(BLOCK / 64) * 3];

    const int b    = blockIdx.y;
    const int tid  = threadIdx.x;
    const int lane = tid & 63;

    if (tid < K) {
        // Same arithmetic as reference: x2 = x + w, area = (x2-x)*(y2-y).
        float4 g = ((const float4*)(gt + (size_t)b * K * 4))[tid];
        float x2 = g.x + g.z, y2 = g.y + g.w;
        gxy_s[tid] = make_float4(g.x, g.y, x2, y2);
        gar_s[tid] = (x2 - g.x) * (y2 - g.y);
    }
    __syncthreads();

    const int tileSz = BLOCK * APT;                 // 2048
    const int ntiles = (A + tileSz - 1) / tileSz;   // 59 at A=120000

    float posf = 0.f, stcs = 0.f, strs = 0.f;

    // One tile per block at the default geometry (gridDim.x == ntiles);
    // loop kept for generality/robustness.
    for (int tt = blockIdx.x; tt < ntiles; tt += gridDim.x) {
        const int base = tt * tileSz + tid;

        float ax[APT], ay[APT], axx[APT], ayy[APT], aar[APT];
        float bi[APT], bd[APT];
        int   bk[APT];
        #pragma unroll
        for (int i = 0; i < APT; ++i) {
            int a  = base + i * BLOCK;
            int ac = a < A ? a : A - 1;  // clamp; contribution guarded later
            float4 an = ((const float4*)anchors)[ac];
            ax[i]  = an.x;         ay[i]  = an.y;
            axx[i] = an.x + an.z;  ayy[i] = an.y + an.w;
            aar[i] = (axx[i] - ax[i]) * (ayy[i] - ay[i]);
            bi[i] = -1.f; bd[i] = 1.f; bk[i] = 0;
        }

        // Hot loop: EXACT r2/r3/r6 structure (proven codegen, no spill).
        // Argmax over iou = inter/(S - inter), S = aar + sar: x/(S-x) is
        // monotone in x/S => candidate beats best <=> inter*bd > bi*S
        // (cross-multiplied, exact operands, no divide). Strict > keeps
        // the first max, matching the reference argmax.
        const int kfull = K & ~(CH - 1);
        for (int k0 = 0; k0 < kfull; k0 += CH) {
            float4 gg[CH];
            float  sar[CH];
            #pragma unroll
            for (int j = 0; j < CH; ++j) {
                gg[j]  = gxy_s[k0 + j];  // ds_read_b128, uniform -> broadcast
                sar[j] = gar_s[k0 + j];  // ds_read_b32
            }
            #pragma unroll
            for (int j = 0; j < CH; ++j) {
                #pragma unroll
                for (int i = 0; i < APT; ++i) {
                    float w = fminf(axx[i], gg[j].z) - fmaxf(ax[i], gg[j].x);
                    float h = fminf(ayy[i], gg[j].w) - fmaxf(ay[i], gg[j].y);
                    w = fmaxf(w, 0.f); h = fmaxf(h, 0.f);
                    float inter = w * h;
                    float S = aar[i] + sar[j];
                    bool better = inter * bd[i] > bi[i] * S;
                    bi[i] = better ? inter : bi[i];
                    bd[i] = better ? S     : bd[i];
                    bk[i] = better ? (k0 + j) : bk[i];
                }
            }
        }
        for (int k = kfull; k < K; ++k) {   // tail (not taken for K=64)
            float4 gg  = gxy_s[k];
            float  sar = gar_s[k];
            #pragma unroll
            for (int i = 0; i < APT; ++i) {
                float w = fminf(axx[i], gg.z) - fmaxf(ax[i], gg.x);
                float h = fminf(ayy[i], gg.w) - fmaxf(ay[i], gg.y);
                w = fmaxf(w, 0.f); h = fmaxf(h, 0.f);
                float inter = w * h;
                float S = aar[i] + sar;
                bool better = inter * bd[i] > bi[i] * S;
                bi[i] = better ? inter : bi[i];
                bd[i] = better ? S     : bd[i];
                bk[i] = better ? k     : bk[i];
            }
        }

        #pragma unroll
        for (int i = 0; i < APT; ++i) {
            int a = base + i * BLOCK;
            // Winner box straight from LDS (divergent one-time gather).
            float4 wb  = gxy_s[bk[i]];
            float  war = gar_s[bk[i]];

            // score == ref max IoU bit-identically: bd-bi = (aar+sar)-inter,
            // same operand order as reference's (area_a + area_g) - inter.
            float score = bi[i] / (bd[i] - bi[i]);
            bool inb = a < A;
            bool pos = inb && (score >= 0.5f);
            bool neg = inb && (score < 0.4f);
            if (pos | neg) {
                const float* sp = ss + ((size_t)b * A + a) * 6;
                float x = sp[4];
                float e = expf(-x);
                float p = 1.f / (1.f + e);
                if (pos) {
                    posf += 1.f;
                    float ce  = log1pf(e);        // softplus(-x) = -log_sigmoid(x)
                    float omp = 1.f - p;
                    stcs += 0.25f * ce * omp * omp;

                    float px  = sp[0], py = sp[1];
                    float pxx = px + sp[2], pyy = py + sp[3];
                    float ew = fminf(pxx, wb.z) - fmaxf(px, wb.x);
                    float eh = fminf(pyy, wb.w) - fmaxf(py, wb.y);
                    ew = fmaxf(ew, 0.f); eh = fmaxf(eh, 0.f);
                    float einter = ew * eh;
                    float pa = (pxx - px) * (pyy - py);
                    float eiou = einter / (pa + war - einter);
                    strs += -logf(eiou + 0.01f);
                } else {
                    float ce = log1pf(expf(x));   // softplus(x) = -log_sigmoid(-x)
                    stcs += 0.75f * ce * p * p;
                }
            }
        }
    }

    // wave64 shuffle reduction -> LDS across waves -> one plain float4 store
    float v0 = posf, v1 = stcs, v2 = strs;
    for (int off = 32; off > 0; off >>= 1) {
        v0 += __shfl_down(v0, off, 64);
        v1 += __shfl_down(v1, off, 64);
        v2 += __shfl_down(v2, off, 64);
    }
    const int wave = tid >> 6;
    if (lane == 0) {
        red[wave * 3 + 0] = v0;
        red[wave * 3 + 1] = v1;
        red[wave * 3 + 2] = v2;
    }
    __syncthreads();
    if (tid == 0) {
        float s0 = 0.f, s1 = 0.f, s2 = 0.f;
        for (int w = 0; w < BLOCK / 64; ++w) {
            s0 += red[w * 3 + 0];
            s1 += red[w * 3 + 1];
            s2 += red[w * 3 + 2];
        }
        // Own slot, plain store: no atomics, no pre-zeroed memory needed.
        ((float4*)part)[(size_t)b * gridDim.x + blockIdx.x] =
            make_float4(s0, s1, s2, 0.f);
    }
}

// Finalize: stream ordering guarantees visibility of main's stores.
// Sums the (B x GX) partial slots and applies the per-batch normalization.
__global__ void ainno_final(const float* __restrict__ part,
                            float* __restrict__ out, int GX, int B)
{
    __shared__ float tot_s[4];
    const int tid = threadIdx.x, lane = tid & 63, wave = tid >> 6; // 4 waves
    float t = 0.f;
    for (int bb = wave; bb < B; bb += 4) {
        float pc = 0.f, st = 0.f, sr = 0.f;
        for (int i = lane; i < GX; i += 64) {
            const float* p = part + ((size_t)bb * GX + i) * 4;
            pc += p[0]; st += p[1]; sr += p[2];
        }
        for (int off = 32; off > 0; off >>= 1) {
            pc += __shfl_down(pc, off, 64);
            st += __shfl_down(st, off, 64);
            sr += __shfl_down(sr, off, 64);
        }
        if (lane == 0) {
            float safe = pc > 0.f ? pc : 1.f;
            float v = st / safe;
            if (pc > 0.f) v += sr / safe;
            t += v;
        }
    }
    if (lane == 0) tot_s[wave] = t;
    __syncthreads();
    if (tid == 0) {
        float s = 0.f;
        for (int w = 0; w < 4; ++w) s += tot_s[w];
        out[0] = s / (float)B;
    }
}

extern "C" void kernel_launch(void* const* d_in, const int* in_sizes, int n_in,
                              void* d_out, int out_size, void* d_ws, size_t ws_size,
                              hipStream_t stream) {
    const float* ss      = (const float*)d_in[0];
    const float* anchors = (const float*)d_in[1];
    const float* gt      = (const float*)d_in[2];
    float* out  = (float*)d_out;
    float* part = (float*)d_ws;

    const int A = in_sizes[1] / 4;
    const int B = in_sizes[0] / (A * 6);
    const int K = in_sizes[2] / (B * 4);

    const int tileSz = BLOCK * APT;                  // 2048
    const int ntiles = (A + tileSz - 1) / tileSz;    // 59 at A=120000
    const int gx     = ntiles;                       // 59*4 = 236 WGs

    dim3 grid(gx, B);
    ainno_main<<<grid, BLOCK, 0, stream>>>(ss, anchors, gt, part, A, K, B);
    ainno_final<<<dim3(1), 256, 0, stream>>>(part, out, gx, B);
}